// Round 1
// baseline (784.796 us; speedup 1.0000x reference)
//
#include <hip/hip_runtime.h>
#include <hip/hip_bf16.h>

#define GHMC_BINS 10
#define GHMC_NT   256
#define GHMC_MAXNB 2048

// Pass 1: grid-stride over float4 groups; per-thread 10-bin {count, bce-sum}
// in registers; wave shuffle-reduce; deterministic per-block partials to ws.
__global__ __launch_bounds__(GHMC_NT) void ghmc_pass1(
    const float* __restrict__ pred,
    const int*   __restrict__ target,
    const float* __restrict__ lw,
    float* __restrict__ sum_part,   // [nb][BINS]
    int*   __restrict__ cnt_part,   // [nb][BINS]
    int nvec4, int nb)
{
    const int tid    = threadIdx.x;
    const int gid    = blockIdx.x * GHMC_NT + tid;
    const int stride = nb * GHMC_NT;

    float lsum[GHMC_BINS];
    int   lcnt[GHMC_BINS];
#pragma unroll
    for (int b = 0; b < GHMC_BINS; ++b) { lsum[b] = 0.0f; lcnt[b] = 0; }

    const float4* p4 = reinterpret_cast<const float4*>(pred);
    const int4*   t4 = reinterpret_cast<const int4*>(target);
    const float4* w4 = reinterpret_cast<const float4*>(lw);

    for (int i = gid; i < nvec4; i += stride) {
        float4 p = p4[i];
        int4   t = t4[i];
        float4 w = w4[i];
        float pp[4] = {p.x, p.y, p.z, p.w};
        int   tt[4] = {t.x, t.y, t.z, t.w};
        float ww[4] = {w.x, w.y, w.z, w.w};
#pragma unroll
        for (int j = 0; j < 4; ++j) {
            float x  = pp[j];
            float tf = (float)tt[j];
            bool valid = ww[j] > 0.0f;
            // sigmoid(x); g = |sig - t| = sigmoid(t ? -(-x) trick): compute directly
            float e   = __expf(-x);
            float sig = __builtin_amdgcn_rcpf(1.0f + e);
            float g   = fabsf(sig - tf);
            int bin = (int)(g * 10.0f);
            bin = bin < 0 ? 0 : (bin > GHMC_BINS - 1 ? GHMC_BINS - 1 : bin);
            // stable BCE-with-logits
            float bce = fmaxf(x, 0.0f) - x * tf + log1pf(__expf(-fabsf(x)));
            float contrib = valid ? bce : 0.0f;
            int   cinc    = valid ? 1 : 0;
#pragma unroll
            for (int b = 0; b < GHMC_BINS; ++b) {
                if (b == bin) { lsum[b] += contrib; lcnt[b] += cinc; }
            }
        }
    }

    // wave (64-lane) butterfly reduce per bin
    __shared__ float ssum[GHMC_NT / 64][GHMC_BINS];
    __shared__ int   scnt[GHMC_NT / 64][GHMC_BINS];
    const int lane = tid & 63;
    const int wave = tid >> 6;
#pragma unroll
    for (int b = 0; b < GHMC_BINS; ++b) {
        float s = lsum[b];
        int   c = lcnt[b];
#pragma unroll
        for (int m = 32; m >= 1; m >>= 1) {
            s += __shfl_xor(s, m, 64);
            c += __shfl_xor(c, m, 64);
        }
        if (lane == 0) { ssum[wave][b] = s; scnt[wave][b] = c; }
    }
    __syncthreads();
    if (tid < GHMC_BINS) {
        float s = 0.0f; int c = 0;
#pragma unroll
        for (int w = 0; w < GHMC_NT / 64; ++w) { s += ssum[w][tid]; c += scnt[w][tid]; }
        sum_part[blockIdx.x * GHMC_BINS + tid] = s;
        cnt_part[blockIdx.x * GHMC_BINS + tid] = c;
    }
}

// Pass 2: one block folds nb x BINS partials -> scalar loss.
__global__ __launch_bounds__(GHMC_NT) void ghmc_pass2(
    const float* __restrict__ sum_part,
    const int*   __restrict__ cnt_part,
    float* __restrict__ out, int nb)
{
    const int tid = threadIdx.x;
    float lsum[GHMC_BINS];
    int   lcnt[GHMC_BINS];
#pragma unroll
    for (int b = 0; b < GHMC_BINS; ++b) { lsum[b] = 0.0f; lcnt[b] = 0; }

    for (int k = tid; k < nb; k += GHMC_NT) {
#pragma unroll
        for (int b = 0; b < GHMC_BINS; ++b) {
            lsum[b] += sum_part[k * GHMC_BINS + b];
            lcnt[b] += cnt_part[k * GHMC_BINS + b];
        }
    }

    __shared__ float ssum[GHMC_NT / 64][GHMC_BINS];
    __shared__ int   scnt[GHMC_NT / 64][GHMC_BINS];
    const int lane = tid & 63;
    const int wave = tid >> 6;
#pragma unroll
    for (int b = 0; b < GHMC_BINS; ++b) {
        float s = lsum[b];
        int   c = lcnt[b];
#pragma unroll
        for (int m = 32; m >= 1; m >>= 1) {
            s += __shfl_xor(s, m, 64);
            c += __shfl_xor(c, m, 64);
        }
        if (lane == 0) { ssum[wave][b] = s; scnt[wave][b] = c; }
    }
    __syncthreads();

    if (tid == 0) {
        float loss = 0.0f;
        int n = 0;
        for (int b = 0; b < GHMC_BINS; ++b) {
            float s = 0.0f; int c = 0;
            for (int w = 0; w < GHMC_NT / 64; ++w) { s += ssum[w][b]; c += scnt[w][b]; }
            if (c > 0) n++;
            loss += s / fmaxf((float)c, 1.0f);
        }
        loss /= (float)(n > 0 ? n : 1);
        out[0] = loss;  // LOSS_WEIGHT = 1.0
    }
}

extern "C" void kernel_launch(void* const* d_in, const int* in_sizes, int n_in,
                              void* d_out, int out_size, void* d_ws, size_t ws_size,
                              hipStream_t stream) {
    const float* pred   = (const float*)d_in[0];
    const int*   target = (const int*)d_in[1];
    const float* lw     = (const float*)d_in[2];
    float* out = (float*)d_out;

    const long long total = (long long)in_sizes[0];   // N*C = 67,108,864
    const int nvec4 = (int)(total / 4);

    // ws layout: float sum_part[nb][BINS] then int cnt_part[nb][BINS]
    int nb = GHMC_MAXNB;
    size_t per_block = (size_t)GHMC_BINS * 8;  // 4B sum + 4B cnt per bin
    if (ws_size < (size_t)nb * per_block) {
        nb = (int)(ws_size / per_block);
        if (nb < 1) nb = 1;
    }
    float* sum_part = (float*)d_ws;
    int*   cnt_part = (int*)((char*)d_ws + (size_t)nb * GHMC_BINS * sizeof(float));

    ghmc_pass1<<<nb, GHMC_NT, 0, stream>>>(pred, target, lw, sum_part, cnt_part, nvec4, nb);
    ghmc_pass2<<<1, GHMC_NT, 0, stream>>>(sum_part, cnt_part, out, nb);
}